// Round 1
// baseline (333.033 us; speedup 1.0000x reference)
//
#include <hip/hip_runtime.h>
#include <stdint.h>

#define T_SEQ 2048
#define DM    2048
#define NH    16
#define NKV   4
#define HD    128
#define MROWS 4096          // B*T
#define NQKV  3072          // 16*128 + 4*128 + 4*128

typedef unsigned short u16;
typedef __bf16 bf16x8 __attribute__((ext_vector_type(8)));
typedef float  f32x4  __attribute__((ext_vector_type(4)));

__device__ __forceinline__ u16 f2b(float f) {
  union { float f; unsigned u; } v; v.f = f;
  return (u16)((v.u + 0x7fffu + ((v.u >> 16) & 1u)) >> 16);
}
__device__ __forceinline__ float b2f(u16 u) {
  union { unsigned u; float f; } v; v.u = ((unsigned)u) << 16;
  return v.f;
}
// async global->LDS, 16B per lane; LDS dest = wave-uniform base + lane*16
__device__ __forceinline__ void gl_lds16(const u16* g, u16* l) {
  __builtin_amdgcn_global_load_lds(
      (__attribute__((address_space(1))) void*)g,
      (__attribute__((address_space(3))) void*)l, 16, 0, 0);
}
__device__ __forceinline__ void storev(float* p, float v) { *p = v; }
__device__ __forceinline__ void storev(u16* p, float v)   { *p = f2b(v); }

// ---- fp32 -> bf16 elementwise (x) ----
__global__ __launch_bounds__(256) void k_cvt_x(const float* __restrict__ x,
                                               u16* __restrict__ o, int n) {
  int i = (blockIdx.x * 256 + threadIdx.x) * 4;
  if (i >= n) return;
  float4 v = *(const float4*)(x + i);
  ushort4 r;
  r.x = f2b(v.x); r.y = f2b(v.y); r.z = f2b(v.z); r.w = f2b(v.w);
  *(ushort4*)(o + i) = r;
}

// ---- all four weight transposes in one launch ----
__global__ __launch_bounds__(256) void k_tw4(const float* __restrict__ Wq,
                                             const float* __restrict__ Wk,
                                             const float* __restrict__ Wv,
                                             const float* __restrict__ Wo,
                                             u16* __restrict__ WT,
                                             u16* __restrict__ Wot) {
  __shared__ float tl[32][33];
  int z = blockIdx.z;
  const float* in; u16* out; int Nd, xt;
  if (z < 64)      { in = Wq; out = WT;               Nd = 2048; xt = z; }
  else if (z < 80) { in = Wk; out = WT + 2048 * 2048; Nd = 512;  xt = z - 64; }
  else if (z < 96) { in = Wv; out = WT + 2560 * 2048; Nd = 512;  xt = z - 80; }
  else             { in = Wo; out = Wot;              Nd = 2048; xt = z - 96; }
  int n0 = xt * 32, k0 = blockIdx.y * 32;
  int tx = threadIdx.x, ty = threadIdx.y;
#pragma unroll
  for (int i = 0; i < 32; i += 8)
    tl[ty + i][tx] = in[(long)(k0 + ty + i) * Nd + n0 + tx];
  __syncthreads();
#pragma unroll
  for (int i = 0; i < 32; i += 8)
    out[(long)(n0 + ty + i) * 2048 + k0 + tx] = f2b(tl[tx][ty + i]);
}

// ---- C[M][N] = A[M][K] * Bt[N][K]^T  -- 8-phase 256-row tile (T2+T3+T4+T5) ----
// 8 waves (2M x 4N), BK=64, per-wave C = 128 x (BN/4). LDS double-buffered,
// staged with global_load_lds (16B) using the 16B-chunk XOR swizzle:
// LDS[row][pos] holds global chunk pos^(row&7); reads XOR the same way
// (both-sides-or-neither, rule #21). ds_read bank-groups land balanced
// (8 lanes x 16B per 4-bank group) -> 0 conflicts (measured on prev kernel).
//
// Phase = { stage 1 half-tile ; ds_read one operand quadrant } -> s_barrier ->
// lgkmcnt(0) -> setprio(1) -> 16(or 8) MFMA (one C-quadrant, full K=64) ->
// setprio(0) -> s_barrier.  Staging stream (steady state, per K-tile t):
//   ph1: A-h0(t+1)  ph2: A-h1(t+1)  ph3: B-h0(t+2)  ph4: B-h1(t+2)
// Region safety: B rows of tile t are last-read in ph2, A rows in ph3; each
// stage lands in a region whose previous readers drained (lgkmcnt(0) before
// the end-of-phase barrier). Sync is ONE counted vmcnt per K-tile at ph4:
// vmcnt(2*BH) leaves the 2 B half-tiles of t+2 in flight across the barrier
// (never vmcnt(0) in steady state). Raw s_barrier (not __syncthreads) so the
// compiler does not force a vmcnt(0) drain.
template <int BN, typename OutT>
__global__ __launch_bounds__(512, 2) void k_gemm8(const u16* __restrict__ A,
                                                  const u16* __restrict__ Bt,
                                                  OutT* __restrict__ C,
                                                  int M, int N, int K) {
  constexpr int NJ = BN / 128;   // B fragments per quadrant (2 or 1)
  constexpr int BH = NJ;         // B half-tiles (128-row units) per K-tile
  __shared__ __align__(16) u16 As[2][256 * 64];
  __shared__ __align__(16) u16 Bs[2][BN * 64];
  const int tid = threadIdx.x;
  const int wv = tid >> 6, lane = tid & 63;
  const int quad = lane >> 4, ln = lane & 15, ln7 = lane & 7 & 7;
  const int wm = wv & 1, wn = wv >> 1;
  const long m0 = (long)blockIdx.x * 256;
  const long n0 = (long)blockIdx.y * BN;
  const int so = wv << 1;             // wave's stage-op pair index
  const int lr8 = lane >> 3;          // lane's row within an 8-row op span
  const int gch = (lane & 7) ^ lr8;   // pre-swizzled global chunk col

  f32x4 acc[8][2 * NJ] = {};
  bf16x8 Af[4][2], Bf[2 * NJ][2];

  auto stage = [&](const u16* __restrict__ G, long grow0, long kcol, u16* lds) {
#pragma unroll
    for (int o = 0; o < 2; ++o) {
      int lr = (so + o) * 8;          // 8-row span; wave-uniform LDS base
      gl_lds16(G + (grow0 + lr + lr8) * (long)K + kcol + gch * 8, lds + lr * 64);
    }
  };

#define READ_A(MH)                                                            \
  _Pragma("unroll") for (int i = 0; i < 4; ++i)                               \
      _Pragma("unroll") for (int s = 0; s < 2; ++s)                           \
          Af[i][s] = *(const bf16x8*)&asc[((MH)*64 + i * 16 + ln) * 64 +      \
                                          (((s * 4 + quad) ^ (ln & 7)) << 3)];
#define READ_B(NHq)                                                           \
  _Pragma("unroll") for (int jj = 0; jj < NJ; ++jj)                           \
      _Pragma("unroll") for (int s = 0; s < 2; ++s)                           \
          Bf[(NHq)*NJ + jj][s] =                                              \
              *(const bf16x8*)&bsc[(((NHq)*NJ + jj) * 16 + ln) * 64 +         \
                                   (((s * 4 + quad) ^ (ln & 7)) << 3)];
#define MMA_Q(MH, NHq)                                                        \
  _Pragma("unroll") for (int i = 0; i < 4; ++i)                               \
      _Pragma("unroll") for (int jj = 0; jj < NJ; ++jj) {                     \
        acc[(MH)*4 + i][(NHq)*NJ + jj] =                                      \
            __builtin_amdgcn_mfma_f32_16x16x32_bf16(                          \
                Af[i][0], Bf[(NHq)*NJ + jj][0],                               \
                acc[(MH)*4 + i][(NHq)*NJ + jj], 0, 0, 0);                     \
        acc[(MH)*4 + i][(NHq)*NJ + jj] =                                      \
            __builtin_amdgcn_mfma_f32_16x16x32_bf16(                          \
                Af[i][1], Bf[(NHq)*NJ + jj][1],                               \
                acc[(MH)*4 + i][(NHq)*NJ + jj], 0, 0, 0);                     \
      }
#define PH_MID()                                                              \
  __builtin_amdgcn_s_barrier();                                               \
  asm volatile("s_waitcnt lgkmcnt(0)" ::: "memory");                          \
  __builtin_amdgcn_s_setprio(1)
#define PH_END()                                                              \
  __builtin_amdgcn_s_setprio(0);                                              \
  __builtin_amdgcn_s_barrier()

  const int NT = K >> 6;
  // prologue: B(0), A(0), B(1) staged; leave B(1) in flight (vmcnt counted)
  stage(Bt, n0, 0, Bs[0]);
  if (BH == 2) stage(Bt, n0 + 128, 0, Bs[0] + 128 * 64);
  stage(A, m0, 0, As[0]);
  stage(A, m0 + 128, 0, As[0] + 128 * 64);
  stage(Bt, n0, 64, Bs[1]);
  if (BH == 2) stage(Bt, n0 + 128, 64, Bs[1] + 128 * 64);
  asm volatile("s_waitcnt vmcnt(%0)" ::"i"(2 * BH) : "memory");
  __builtin_amdgcn_s_barrier();

  for (int t = 0; t < NT; ++t) {
    const int par = t & 1;
    const u16* asc = As[par] + wm * (128 * 64);
    const u16* bsc = Bs[par] + wn * (32 * NJ * 64);
    u16* an = As[par ^ 1];
    u16* bp = Bs[par];
    const bool pa = (t + 1 < NT), pb = (t + 2 < NT);
    // ---- phase 1: quadrant (0,0) ----
    if (pa) stage(A, m0, (long)(t + 1) * 64, an);
    READ_A(0); READ_B(0);
    PH_MID(); MMA_Q(0, 0); PH_END();
    // ---- phase 2: quadrant (0,1) ----
    if (pa) stage(A, m0 + 128, (long)(t + 1) * 64, an + 128 * 64);
    READ_B(1);
    PH_MID(); MMA_Q(0, 1); PH_END();
    // ---- phase 3: quadrant (1,1) ----
    if (pb) stage(Bt, n0, (long)(t + 2) * 64, bp);
    READ_A(1);
    PH_MID(); MMA_Q(1, 1); PH_END();
    // ---- phase 4: quadrant (1,0), per-K-tile counted vmcnt sync ----
    if (BH == 2 && pb) stage(Bt, n0 + 128, (long)(t + 2) * 64, bp + 128 * 64);
    if (pb) asm volatile("s_waitcnt vmcnt(%0)" ::"i"(2 * BH) : "memory");
    else    asm volatile("s_waitcnt vmcnt(0)" ::: "memory");
    PH_MID(); MMA_Q(1, 0); PH_END();
  }
#undef READ_A
#undef READ_B
#undef MMA_Q
#undef PH_MID
#undef PH_END
  (void)ln7;
#pragma unroll
  for (int i = 0; i < 8; ++i) {
    long row = m0 + wm * 128 + i * 16 + quad * 4;
#pragma unroll
    for (int j = 0; j < 2 * NJ; ++j) {
      long col = n0 + wn * (32 * NJ) + j * 16 + ln;
#pragma unroll
      for (int r = 0; r < 4; ++r)
        storev(&C[(row + r) * N + col], acc[i][j][r]);
    }
  }
}

// ---- fused RoPE for Q (16 heads, pre-scaled) and K (4 kv heads) ----
__global__ __launch_bounds__(256) void k_rope2(const u16* __restrict__ C,
                                               u16* __restrict__ Qo,
                                               u16* __restrict__ Ko) {
  int idx = blockIdx.x * 256 + threadIdx.x;
  int d = idx & 63;
  int t = (idx >> 6) & (T_SEQ - 1);
  int g = idx >> 17;            // 0..39 : b*20 + hh
  int b = (g >= 20) ? 1 : 0;
  int hh = g - b * 20;
  int isQ = hh < 16;
  int head = isQ ? hh : (hh - 16);
  int coloff = isQ ? 0 : 2048;
  float qscale = isQ ? 0.12751745f : 1.0f;   // (1/sqrt(128))*log2(e)
  u16* o = isQ ? Qo : Ko;
  int nh = isQ ? NH : NKV;
  long inb = (long)(b * T_SEQ + t) * NQKV + coloff + head * HD + d;
  float q1 = b2f(C[inb]);
  float q2 = b2f(C[inb + 64]);
  float inv = __expf(-0.14391156f * (float)d);  // 10000^(-d/64)
  float sn, cs;
  __sincosf((float)t * inv, &sn, &cs);
  long ob = (((long)b * nh + head) * T_SEQ + t) * HD + d;
  o[ob]      = f2b((q1 * cs - q2 * sn) * qscale);
  o[ob + 64] = f2b((q2 * cs + q1 * sn) * qscale);
}

// ---- V columns of Cqkv -> Vt [B,KV,hd,T] ----
__global__ __launch_bounds__(256) void k_vt(const u16* __restrict__ C,
                                            u16* __restrict__ Vt) {
  __shared__ u16 tl[32][33];
  int bkv = blockIdx.z;
  int t0 = blockIdx.x * 32, d0 = blockIdx.y * 32;
  int tx = threadIdx.x, ty = threadIdx.y;
  int b = bkv >> 2, kv = bkv & 3;
#pragma unroll
  for (int i = 0; i < 32; i += 8)
    tl[ty + i][tx] = C[(long)(b * T_SEQ + t0 + ty + i) * NQKV + 2560 + kv * HD + d0 + tx];
  __syncthreads();
#pragma unroll
  for (int i = 0; i < 32; i += 8)
    Vt[((long)bkv * HD + d0 + ty + i) * T_SEQ + t0 + tx] = tl[tx][ty + i];
}

// ---- fixed-rebase P emit for one 16x64 score strip ----
template <bool DIAG>
__device__ __forceinline__ void p_emit(f32x4 (&S)[4], u16* __restrict__ Pb,
                                       int quad, int ln, int mrow) {
#pragma unroll
  for (int nt = 0; nt < 4; ++nt)
#pragma unroll
    for (int r = 0; r < 4; ++r) {
      float v = S[nt][r];
      if (DIAG) v = (nt * 16 + ln <= mrow + r) ? v : -1e30f;
      float pv = exp2f(v - 8.0f);
      int row = quad * 4 + r;
      int chnk = (nt * 2 + (ln >> 3)) ^ (row & 7);
      *(__bf16*)&Pb[row * 64 + chnk * 8 + (ln & 7)] = (__bf16)pv;
    }
}

// ---- causal GQA flash attention: pair-balanced, fixed-rebase softmax ----
__global__ __launch_bounds__(256, 2) void k_attn(const u16* __restrict__ Q,
                                                 const u16* __restrict__ Kg,
                                                 const u16* __restrict__ Vt,
                                                 u16* __restrict__ Og) {
  __shared__ __align__(16) u16 Ks[64 * 128];     // [key][hd], swizzled chunks
  __shared__ __align__(16) u16 Vs[128 * 64];     // [hd][key], swizzled chunks
  __shared__ __align__(16) u16 Ps[4][2][16 * 64]; // per-wave, per-strip P
  const int tid = threadIdx.x;
  const int wv = tid >> 6, lane = tid & 63;
  const int quad = lane >> 4, ln = lane & 15;
  const int bh = blockIdx.y;
  const int b = bh >> 4, h = bh & 15;
  const int kvh = h >> 2;
  const int p = blockIdx.x;
  const int thi = 31 - p, tlo = p;
  const int qhi = thi * 64 + wv * 16;   // global q-row base, hi strip
  const int qlo = tlo * 64 + wv * 16;

  bf16x8 qfh[4], qfl[4];
  {
    const u16* qp = Q + ((long)bh * T_SEQ + qhi + ln) * HD + quad * 8;
#pragma unroll
    for (int s = 0; s < 4; ++s) qfh[s] = *(const bf16x8*)(qp + s * 32);
    qp = Q + ((long)bh * T_SEQ + qlo + ln) * HD + quad * 8;
#pragma unroll
    for (int s = 0; s < 4; ++s) qfl[s] = *(const bf16x8*)(qp + s * 32);
  }
  bf16x8 onesb;
#pragma unroll
  for (int i = 0; i < 8; ++i) onesb[i] = (__bf16)1.0f;

  f32x4 lh = {0.f, 0.f, 0.f, 0.f}, ll = {0.f, 0.f, 0.f, 0.f};
  f32x4 oh[8] = {}, ol[8] = {};

  const u16* Kb = Kg + (long)(b * NKV + kvh) * T_SEQ * HD;
  const u16* Vb = Vt + (long)(b * NKV + kvh) * HD * T_SEQ;

  for (int kt = 0; kt <= thi; ++kt) {
    const int k0 = kt * 64;
#pragma unroll
    for (int r = 0; r < 4; ++r) {
      int s = r * 256 + tid;
      gl_lds16(Kb + (long)(k0 + (s >> 4)) * HD + (((s & 15) ^ ((s >> 4) & 15)) << 3),
               &Ks[(r * 256 + wv * 64) * 8]);
      gl_lds16(Vb + (long)(s >> 3) * T_SEQ + k0 + (((s & 7) ^ ((s >> 3) & 7)) << 3),
               &Vs[(r * 256 + wv * 64) * 8]);
    }
    __syncthreads();
    const bool lo_act = (kt <= tlo);
    f32x4 Sh[4], Sl[4];
#pragma unroll
    for (int nt = 0; nt < 4; ++nt) {
      bf16x8 kb[4];
      const u16* kp = &Ks[(nt * 16 + ln) * 128];
#pragma unroll
      for (int ss = 0; ss < 4; ++ss)
        kb[ss] = *(const bf16x8*)(kp + (((quad + 4 * ss) ^ ln) << 3));
      f32x4 s = {0.f, 0.f, 0.f, 0.f};
#pragma unroll
      for (int ss = 0; ss < 4; ++ss)
        s = __builtin_amdgcn_mfma_f32_16x16x32_bf16(qfh[ss], kb[ss], s, 0, 0, 0);
      Sh[nt] = s;
      if (lo_act) {
        f32x4 t = {0.f, 0.f, 0.f, 0.f};
#pragma unroll
        for (int ss = 0; ss < 4; ++ss)
          t = __builtin_amdgcn_mfma_f32_16x16x32_bf16(qfl[ss], kb[ss], t, 0, 0, 0);
        Sl[nt] = t;
      }
    }
    if (kt == thi) p_emit<true>(Sh, &Ps[wv][0][0], quad, ln, wv * 16 + quad * 4);
    else           p_emit<false>(Sh, &Ps[wv][0][0], quad, ln, 0);
    if (lo_act) {
      if (kt == tlo) p_emit<true>(Sl, &Ps[wv][1][0], quad, ln, wv * 16 + quad * 4);
      else           p_emit<false>(Sl, &Ps[wv][1][0], quad, ln, 0);
    }
    asm volatile("s_waitcnt lgkmcnt(0)" ::: "memory");
    bf16x8 pfh[2], pfl[2];
#pragma unroll
    for (int ss = 0; ss < 2; ++ss)
      pfh[ss] = *(const bf16x8*)&Ps[wv][0][ln * 64 + (((ss * 4 + quad) ^ (ln & 7)) << 3)];
    if (lo_act) {
#pragma unroll
      for (int ss = 0; ss < 2; ++ss)
        pfl[ss] = *(const bf16x8*)&Ps[wv][1][ln * 64 + (((ss * 4 + quad) ^ (ln & 7)) << 3)];
    }
    lh = __builtin_amdgcn_mfma_f32_16x16x32_bf16(pfh[0], onesb, lh, 0, 0, 0);
    lh = __builtin_amdgcn_mfma_f32_16x16x32_bf16(pfh[1], onesb, lh, 0, 0, 0);
    if (lo_act) {
      ll = __builtin_amdgcn_mfma_f32_16x16x32_bf16(pfl[0], onesb, ll, 0, 0, 0);
      ll = __builtin_amdgcn_mfma_f32_16x16x32_bf16(pfl[1], onesb, ll, 0, 0, 0);
    }
#pragma unroll
    for (int dt = 0; dt < 8; ++dt) {
      bf16x8 vb[2];
      const u16* vp = &Vs[(dt * 16 + ln) * 64];
#pragma unroll
      for (int ss = 0; ss < 2; ++ss)
        vb[ss] = *(const bf16x8*)(vp + (((quad + 4 * ss) ^ (ln & 7)) << 3));
#pragma unroll
      for (int ss = 0; ss < 2; ++ss)
        oh[dt] = __builtin_amdgcn_mfma_f32_16x16x32_bf16(pfh[ss], vb[ss], oh[dt], 0, 0, 0);
      if (lo_act) {
#pragma unroll
        for (int ss = 0; ss < 2; ++ss)
          ol[dt] = __builtin_amdgcn_mfma_f32_16x16x32_bf16(pfl[ss], vb[ss], ol[dt], 0, 0, 0);
      }
    }
    __syncthreads();
  }
  float rh[4], rl[4];
#pragma unroll
  for (int r = 0; r < 4; ++r) { rh[r] = 1.f / lh[r]; rl[r] = 1.f / ll[r]; }
#pragma unroll
  for (int dt = 0; dt < 8; ++dt)
#pragma unroll
    for (int r = 0; r < 4; ++r) {
      long rowh = (long)b * T_SEQ + qhi + quad * 4 + r;
      long rowl = (long)b * T_SEQ + qlo + quad * 4 + r;
      Og[rowh * (NH * HD) + h * HD + dt * 16 + ln] = f2b(oh[dt][r] * rh[r]);
      Og[rowl * (NH * HD) + h * HD + dt * 16 + ln] = f2b(ol[dt][r] * rl[r]);
    }
}

extern "C" void kernel_launch(void* const* d_in, const int* in_sizes, int n_in,
                              void* d_out, int out_size, void* d_ws, size_t ws_size,
                              hipStream_t stream) {
  const float* x  = (const float*)d_in[0];
  const float* Wq = (const float*)d_in[1];
  const float* Wk = (const float*)d_in[2];
  const float* Wv = (const float*)d_in[3];
  const float* Wo = (const float*)d_in[4];
  float* out = (float*)d_out;
  char* ws = (char*)d_ws;
  // workspace layout (bytes)
  u16* WT  = (u16*)(ws + 0);          // [3072][2048] bf16  (Wq^T | Wk^T | Wv^T)
  u16* Wot = (u16*)(ws + 12582912);   // [2048][2048] bf16
  u16* Cq  = (u16*)(ws + 20971520);   // [4096][3072] bf16 ; later attn [4096][2048]
  u16* Xb  = (u16*)(ws + 46137344);   // [4096][2048] bf16 ; later Q [B,NH,T,HD]
  u16* Kb  = (u16*)(ws + 62914560);   // [B,NKV,T,HD] bf16
  u16* Vtb = (u16*)(ws + 67108864);   // [B,NKV,HD,T] bf16
  u16* Qb = Xb;    // alias: Xb dead after QKV GEMM
  u16* attn = Cq;  // alias: Cqkv dead after rope/vtrans

  k_cvt_x<<<8192, 256, 0, stream>>>(x, Xb, MROWS * DM);
  k_tw4<<<dim3(1, 64, 160), dim3(32, 8), 0, stream>>>(Wq, Wk, Wv, Wo, WT, Wot);

  // QKV projection: 256x256 tiles -> 16x12 = 192 blocks
  k_gemm8<256, u16><<<dim3(16, 12), 512, 0, stream>>>(Xb, WT, Cq, MROWS, NQKV, DM);

  k_rope2<<<20480, 256, 0, stream>>>(Cq, Qb, Kb);
  k_vt<<<dim3(64, 4, 8), dim3(32, 8), 0, stream>>>(Cq, Vtb);

  k_attn<<<dim3(16, 32), 256, 0, stream>>>(Qb, Kb, Vtb, attn);

  // output projection: 256x128 tiles -> 16x16 = 256 blocks (exactly 1/CU)
  k_gemm8<128, float><<<dim3(16, 16), 512, 0, stream>>>(attn, Wot, out, MROWS, DM, 2048);
}

// Round 2
// 310.303 us; speedup vs baseline: 1.0733x; 1.0733x over previous
//
#include <hip/hip_runtime.h>
#include <stdint.h>

#define T_SEQ 2048
#define DM    2048
#define NH    16
#define NKV   4
#define HD    128
#define MROWS 4096          // B*T
#define NQKV  3072          // 16*128 + 4*128 + 4*128

typedef unsigned short u16;
typedef __bf16 bf16x8 __attribute__((ext_vector_type(8)));
typedef float  f32x4  __attribute__((ext_vector_type(4)));

__device__ __forceinline__ u16 f2b(float f) {
  union { float f; unsigned u; } v; v.f = f;
  return (u16)((v.u + 0x7fffu + ((v.u >> 16) & 1u)) >> 16);
}
__device__ __forceinline__ float b2f(u16 u) {
  union { unsigned u; float f; } v; v.u = ((unsigned)u) << 16;
  return v.f;
}
// async global->LDS, 16B per lane; LDS dest = wave-uniform base + lane*16
__device__ __forceinline__ void gl_lds16(const u16* g, u16* l) {
  __builtin_amdgcn_global_load_lds(
      (__attribute__((address_space(1))) void*)g,
      (__attribute__((address_space(3))) void*)l, 16, 0, 0);
}
__device__ __forceinline__ void storev(float* p, float v) { *p = v; }
__device__ __forceinline__ void storev(u16* p, float v)   { *p = f2b(v); }

// ---- fp32 -> bf16 elementwise (x) ----
__global__ __launch_bounds__(256) void k_cvt_x(const float* __restrict__ x,
                                               u16* __restrict__ o, int n) {
  int i = (blockIdx.x * 256 + threadIdx.x) * 4;
  if (i >= n) return;
  float4 v = *(const float4*)(x + i);
  ushort4 r;
  r.x = f2b(v.x); r.y = f2b(v.y); r.z = f2b(v.z); r.w = f2b(v.w);
  *(ushort4*)(o + i) = r;
}

// ---- all four weight transposes in one launch ----
__global__ __launch_bounds__(256) void k_tw4(const float* __restrict__ Wq,
                                             const float* __restrict__ Wk,
                                             const float* __restrict__ Wv,
                                             const float* __restrict__ Wo,
                                             u16* __restrict__ WT,
                                             u16* __restrict__ Wot) {
  __shared__ float tl[32][33];
  int z = blockIdx.z;
  const float* in; u16* out; int Nd, xt;
  if (z < 64)      { in = Wq; out = WT;               Nd = 2048; xt = z; }
  else if (z < 80) { in = Wk; out = WT + 2048 * 2048; Nd = 512;  xt = z - 64; }
  else if (z < 96) { in = Wv; out = WT + 2560 * 2048; Nd = 512;  xt = z - 80; }
  else             { in = Wo; out = Wot;              Nd = 2048; xt = z - 96; }
  int n0 = xt * 32, k0 = blockIdx.y * 32;
  int tx = threadIdx.x, ty = threadIdx.y;
#pragma unroll
  for (int i = 0; i < 32; i += 8)
    tl[ty + i][tx] = in[(long)(k0 + ty + i) * Nd + n0 + tx];
  __syncthreads();
#pragma unroll
  for (int i = 0; i < 32; i += 8)
    out[(long)(n0 + ty + i) * 2048 + k0 + tx] = f2b(tl[tx][ty + i]);
}

// ---- C[M][N] = A[M][K] * Bt[N][K]^T  -- 256-row tile, phase-pipelined ----
// 8 waves (2M x 4N), BK=64, double-buffered LDS with 16B-chunk XOR swizzle
// (both-sides: pre-swizzled global source + swizzled ds_read).
//
// KEY FIX vs the round-1 regression: BOTH operands now prefetch at distance
// 2 K-tiles. A(t)'s LDS is fully read after ph3 and B(t)'s after ph2, so
// B(t+2) stages at ph3 and A(t+2) at ph4 into buffer [t&1] (same parity).
// The per-K-tile sync is vmcnt(8): tile t+1 (issued a FULL K-tile earlier,
// ~5-8 phases of cover) drains; tile t+2 (8 ops) stays in flight across the
// barrier. Round 1 waited on loads issued only 2-3 phases prior -> exposed
// load latency every tile (MfmaUtil 24%, all-idle).
//
// NJ==2 (BN=256): 4 phases/K-tile, 16 MFMA each.
// NJ==1 (BN=128): 2 phases/K-tile, 16 MFMA each (A dist-1 at ph1, B dist-2).
template <int BN, typename OutT>
__global__ __launch_bounds__(512, 2) void k_gemm8(const u16* __restrict__ A,
                                                  const u16* __restrict__ Bt,
                                                  OutT* __restrict__ C,
                                                  int M, int N, int K) {
  constexpr int NJ = BN / 128;   // B fragments per quadrant (2 or 1)
  __shared__ __align__(16) u16 As[2][256 * 64];
  __shared__ __align__(16) u16 Bs[2][BN * 64];
  const int tid = threadIdx.x;
  const int wv = tid >> 6, lane = tid & 63;
  const int quad = lane >> 4, ln = lane & 15;
  const int wm = wv & 1, wn = wv >> 1;
  const long m0 = (long)blockIdx.x * 256;
  const long n0 = (long)blockIdx.y * BN;
  const int so = wv << 1;             // wave's stage-op pair index
  const int lr8 = lane >> 3;          // lane's row within an 8-row op span
  const int gch = (lane & 7) ^ lr8;   // pre-swizzled global chunk col

  f32x4 acc[8][2 * NJ] = {};
  bf16x8 Af[4][2], Bf[2 * NJ][2];

  auto stage = [&](const u16* __restrict__ G, long grow0, long kcol, u16* lds) {
#pragma unroll
    for (int o = 0; o < 2; ++o) {
      int lr = (so + o) * 8;          // 8-row span; wave-uniform LDS base
      gl_lds16(G + (grow0 + lr + lr8) * (long)K + kcol + gch * 8, lds + lr * 64);
    }
  };

#define READ_A(MH)                                                            \
  _Pragma("unroll") for (int i = 0; i < 4; ++i)                               \
      _Pragma("unroll") for (int s = 0; s < 2; ++s)                           \
          Af[i][s] = *(const bf16x8*)&asc[((MH)*64 + i * 16 + ln) * 64 +      \
                                          (((s * 4 + quad) ^ (ln & 7)) << 3)];
#define READ_B(NHq)                                                           \
  _Pragma("unroll") for (int jj = 0; jj < NJ; ++jj)                           \
      _Pragma("unroll") for (int s = 0; s < 2; ++s)                           \
          Bf[(NHq)*NJ + jj][s] =                                              \
              *(const bf16x8*)&bsc[(((NHq)*NJ + jj) * 16 + ln) * 64 +         \
                                   (((s * 4 + quad) ^ (ln & 7)) << 3)];
#define MMA_Q(MH, NHq)                                                        \
  _Pragma("unroll") for (int i = 0; i < 4; ++i)                               \
      _Pragma("unroll") for (int jj = 0; jj < NJ; ++jj) {                     \
        acc[(MH)*4 + i][(NHq)*NJ + jj] =                                      \
            __builtin_amdgcn_mfma_f32_16x16x32_bf16(                          \
                Af[i][0], Bf[(NHq)*NJ + jj][0],                               \
                acc[(MH)*4 + i][(NHq)*NJ + jj], 0, 0, 0);                     \
        acc[(MH)*4 + i][(NHq)*NJ + jj] =                                      \
            __builtin_amdgcn_mfma_f32_16x16x32_bf16(                          \
                Af[i][1], Bf[(NHq)*NJ + jj][1],                               \
                acc[(MH)*4 + i][(NHq)*NJ + jj], 0, 0, 0);                     \
      }
#define PH_MID()                                                              \
  __builtin_amdgcn_s_barrier();                                               \
  asm volatile("s_waitcnt lgkmcnt(0)" ::: "memory");                          \
  __builtin_amdgcn_s_setprio(1)
#define PH_END()                                                              \
  __builtin_amdgcn_s_setprio(0);                                              \
  __builtin_amdgcn_s_barrier()

  const int NT = K >> 6;
  if constexpr (NJ == 2) {
    // prologue: full tile0 -> buf0, full tile1 -> buf1; tile1 stays in flight
    stage(Bt, n0, 0, Bs[0]); stage(Bt, n0 + 128, 0, Bs[0] + 128 * 64);
    stage(A,  m0, 0, As[0]); stage(A,  m0 + 128, 0, As[0] + 128 * 64);
    stage(Bt, n0, 64, Bs[1]); stage(Bt, n0 + 128, 64, Bs[1] + 128 * 64);
    stage(A,  m0, 64, As[1]); stage(A,  m0 + 128, 64, As[1] + 128 * 64);
    asm volatile("s_waitcnt vmcnt(8)" ::: "memory");
    __builtin_amdgcn_s_barrier();

    for (int t = 0; t < NT; ++t) {
      const int par = t & 1;
      const u16* asc = As[par] + wm * (128 * 64);
      const u16* bsc = Bs[par] + wn * (32 * NJ * 64);
      u16* sa = As[par];            // A(t+2) target (same parity as t)
      u16* sb = Bs[par];            // B(t+2) target
      const bool pf = (t + 2 < NT);
      const long kc2 = (long)(t + 2) * 64;
      // ---- phase 1: quadrant (0,0) ----
      READ_A(0); READ_B(0);
      PH_MID(); MMA_Q(0, 0); PH_END();
      // ---- phase 2: quadrant (0,1) ----
      READ_B(1);
      PH_MID(); MMA_Q(0, 1); PH_END();
      // ---- phase 3: quadrant (1,1); B(t) fully read -> stage B(t+2) ----
      if (pf) { stage(Bt, n0, kc2, sb); stage(Bt, n0 + 128, kc2, sb + 128 * 64); }
      READ_A(1);
      PH_MID(); MMA_Q(1, 1); PH_END();
      // ---- phase 4: quadrant (1,0); A(t) fully read -> stage A(t+2);
      //      drain tile t+1 (issued one K-tile ago), keep t+2 in flight ----
      if (pf) { stage(A, m0, kc2, sa); stage(A, m0 + 128, kc2, sa + 128 * 64); }
      if (pf) asm volatile("s_waitcnt vmcnt(8)" ::: "memory");
      else    asm volatile("s_waitcnt vmcnt(0)" ::: "memory");
      PH_MID(); MMA_Q(1, 0); PH_END();
    }
  } else {
    // prologue: tile0 (A h0,h1 + B) -> buf0; B(1) -> buf1 (in flight)
    stage(A,  m0, 0, As[0]); stage(A, m0 + 128, 0, As[0] + 128 * 64);
    stage(Bt, n0, 0, Bs[0]);
    stage(Bt, n0, 64, Bs[1]);
    asm volatile("s_waitcnt vmcnt(2)" ::: "memory");
    __builtin_amdgcn_s_barrier();

    for (int t = 0; t < NT; ++t) {
      const int par = t & 1;
      const u16* asc = As[par] + wm * (128 * 64);
      const u16* bsc = Bs[par] + wn * (32 * NJ * 64);
      const bool pa = (t + 1 < NT), pb = (t + 2 < NT);
      // ---- phase 1: M-half 0, both N-quadrants; stage A(t+1) ----
      if (pa) {
        stage(A, m0,       (long)(t + 1) * 64, As[par ^ 1]);
        stage(A, m0 + 128, (long)(t + 1) * 64, As[par ^ 1] + 128 * 64);
      }
      READ_A(0); READ_B(0); READ_B(1);
      PH_MID(); MMA_Q(0, 0); MMA_Q(0, 1); PH_END();
      // ---- phase 2: M-half 1; B(t) fully read -> stage B(t+2);
      //      drain A(t+1)+B(t+1), keep B(t+2) in flight ----
      if (pb) stage(Bt, n0, (long)(t + 2) * 64, Bs[par]);
      READ_A(1);
      if (pb) asm volatile("s_waitcnt vmcnt(2)" ::: "memory");
      else    asm volatile("s_waitcnt vmcnt(0)" ::: "memory");
      PH_MID(); MMA_Q(1, 0); MMA_Q(1, 1); PH_END();
    }
  }
#undef READ_A
#undef READ_B
#undef MMA_Q
#undef PH_MID
#undef PH_END
#pragma unroll
  for (int i = 0; i < 8; ++i) {
    long row = m0 + wm * 128 + i * 16 + quad * 4;
#pragma unroll
    for (int j = 0; j < 2 * NJ; ++j) {
      long col = n0 + wn * (32 * NJ) + j * 16 + ln;
#pragma unroll
      for (int r = 0; r < 4; ++r)
        storev(&C[(row + r) * N + col], acc[i][j][r]);
    }
  }
}

// ---- fused RoPE for Q (16 heads, pre-scaled) and K (4 kv heads) ----
__global__ __launch_bounds__(256) void k_rope2(const u16* __restrict__ C,
                                               u16* __restrict__ Qo,
                                               u16* __restrict__ Ko) {
  int idx = blockIdx.x * 256 + threadIdx.x;
  int d = idx & 63;
  int t = (idx >> 6) & (T_SEQ - 1);
  int g = idx >> 17;            // 0..39 : b*20 + hh
  int b = (g >= 20) ? 1 : 0;
  int hh = g - b * 20;
  int isQ = hh < 16;
  int head = isQ ? hh : (hh - 16);
  int coloff = isQ ? 0 : 2048;
  float qscale = isQ ? 0.12751745f : 1.0f;   // (1/sqrt(128))*log2(e)
  u16* o = isQ ? Qo : Ko;
  int nh = isQ ? NH : NKV;
  long inb = (long)(b * T_SEQ + t) * NQKV + coloff + head * HD + d;
  float q1 = b2f(C[inb]);
  float q2 = b2f(C[inb + 64]);
  float inv = __expf(-0.14391156f * (float)d);  // 10000^(-d/64)
  float sn, cs;
  __sincosf((float)t * inv, &sn, &cs);
  long ob = (((long)b * nh + head) * T_SEQ + t) * HD + d;
  o[ob]      = f2b((q1 * cs - q2 * sn) * qscale);
  o[ob + 64] = f2b((q2 * cs + q1 * sn) * qscale);
}

// ---- V columns of Cqkv -> Vt [B,KV,hd,T] ----
__global__ __launch_bounds__(256) void k_vt(const u16* __restrict__ C,
                                            u16* __restrict__ Vt) {
  __shared__ u16 tl[32][33];
  int bkv = blockIdx.z;
  int t0 = blockIdx.x * 32, d0 = blockIdx.y * 32;
  int tx = threadIdx.x, ty = threadIdx.y;
  int b = bkv >> 2, kv = bkv & 3;
#pragma unroll
  for (int i = 0; i < 32; i += 8)
    tl[ty + i][tx] = C[(long)(b * T_SEQ + t0 + ty + i) * NQKV + 2560 + kv * HD + d0 + tx];
  __syncthreads();
#pragma unroll
  for (int i = 0; i < 32; i += 8)
    Vt[((long)bkv * HD + d0 + ty + i) * T_SEQ + t0 + tx] = tl[tx][ty + i];
}

// ---- fixed-rebase P emit for one 16x64 score strip ----
template <bool DIAG>
__device__ __forceinline__ void p_emit(f32x4 (&S)[4], u16* __restrict__ Pb,
                                       int quad, int ln, int mrow) {
#pragma unroll
  for (int nt = 0; nt < 4; ++nt)
#pragma unroll
    for (int r = 0; r < 4; ++r) {
      float v = S[nt][r];
      if (DIAG) v = (nt * 16 + ln <= mrow + r) ? v : -1e30f;
      float pv = exp2f(v - 8.0f);
      int row = quad * 4 + r;
      int chnk = (nt * 2 + (ln >> 3)) ^ (row & 7);
      *(__bf16*)&Pb[row * 64 + chnk * 8 + (ln & 7)] = (__bf16)pv;
    }
}

// ---- causal GQA flash attention: pair-balanced, fixed-rebase softmax ----
__global__ __launch_bounds__(256, 2) void k_attn(const u16* __restrict__ Q,
                                                 const u16* __restrict__ Kg,
                                                 const u16* __restrict__ Vt,
                                                 u16* __restrict__ Og) {
  __shared__ __align__(16) u16 Ks[64 * 128];     // [key][hd], swizzled chunks
  __shared__ __align__(16) u16 Vs[128 * 64];     // [hd][key], swizzled chunks
  __shared__ __align__(16) u16 Ps[4][2][16 * 64]; // per-wave, per-strip P
  const int tid = threadIdx.x;
  const int wv = tid >> 6, lane = tid & 63;
  const int quad = lane >> 4, ln = lane & 15;
  const int bh = blockIdx.y;
  const int b = bh >> 4, h = bh & 15;
  const int kvh = h >> 2;
  const int p = blockIdx.x;
  const int thi = 31 - p, tlo = p;
  const int qhi = thi * 64 + wv * 16;   // global q-row base, hi strip
  const int qlo = tlo * 64 + wv * 16;

  bf16x8 qfh[4], qfl[4];
  {
    const u16* qp = Q + ((long)bh * T_SEQ + qhi + ln) * HD + quad * 8;
#pragma unroll
    for (int s = 0; s < 4; ++s) qfh[s] = *(const bf16x8*)(qp + s * 32);
    qp = Q + ((long)bh * T_SEQ + qlo + ln) * HD + quad * 8;
#pragma unroll
    for (int s = 0; s < 4; ++s) qfl[s] = *(const bf16x8*)(qp + s * 32);
  }
  bf16x8 onesb;
#pragma unroll
  for (int i = 0; i < 8; ++i) onesb[i] = (__bf16)1.0f;

  f32x4 lh = {0.f, 0.f, 0.f, 0.f}, ll = {0.f, 0.f, 0.f, 0.f};
  f32x4 oh[8] = {}, ol[8] = {};

  const u16* Kb = Kg + (long)(b * NKV + kvh) * T_SEQ * HD;
  const u16* Vb = Vt + (long)(b * NKV + kvh) * HD * T_SEQ;

  for (int kt = 0; kt <= thi; ++kt) {
    const int k0 = kt * 64;
#pragma unroll
    for (int r = 0; r < 4; ++r) {
      int s = r * 256 + tid;
      gl_lds16(Kb + (long)(k0 + (s >> 4)) * HD + (((s & 15) ^ ((s >> 4) & 15)) << 3),
               &Ks[(r * 256 + wv * 64) * 8]);
      gl_lds16(Vb + (long)(s >> 3) * T_SEQ + k0 + (((s & 7) ^ ((s >> 3) & 7)) << 3),
               &Vs[(r * 256 + wv * 64) * 8]);
    }
    __syncthreads();
    const bool lo_act = (kt <= tlo);
    f32x4 Sh[4], Sl[4];
#pragma unroll
    for (int nt = 0; nt < 4; ++nt) {
      bf16x8 kb[4];
      const u16* kp = &Ks[(nt * 16 + ln) * 128];
#pragma unroll
      for (int ss = 0; ss < 4; ++ss)
        kb[ss] = *(const bf16x8*)(kp + (((quad + 4 * ss) ^ ln) << 3));
      f32x4 s = {0.f, 0.f, 0.f, 0.f};
#pragma unroll
      for (int ss = 0; ss < 4; ++ss)
        s = __builtin_amdgcn_mfma_f32_16x16x32_bf16(qfh[ss], kb[ss], s, 0, 0, 0);
      Sh[nt] = s;
      if (lo_act) {
        f32x4 t = {0.f, 0.f, 0.f, 0.f};
#pragma unroll
        for (int ss = 0; ss < 4; ++ss)
          t = __builtin_amdgcn_mfma_f32_16x16x32_bf16(qfl[ss], kb[ss], t, 0, 0, 0);
        Sl[nt] = t;
      }
    }
    if (kt == thi) p_emit<true>(Sh, &Ps[wv][0][0], quad, ln, wv * 16 + quad * 4);
    else           p_emit<false>(Sh, &Ps[wv][0][0], quad, ln, 0);
    if (lo_act) {
      if (kt == tlo) p_emit<true>(Sl, &Ps[wv][1][0], quad, ln, wv * 16 + quad * 4);
      else           p_emit<false>(Sl, &Ps[wv][1][0], quad, ln, 0);
    }
    asm volatile("s_waitcnt lgkmcnt(0)" ::: "memory");
    bf16x8 pfh[2], pfl[2];
#pragma unroll
    for (int ss = 0; ss < 2; ++ss)
      pfh[ss] = *(const bf16x8*)&Ps[wv][0][ln * 64 + (((ss * 4 + quad) ^ (ln & 7)) << 3)];
    if (lo_act) {
#pragma unroll
      for (int ss = 0; ss < 2; ++ss)
        pfl[ss] = *(const bf16x8*)&Ps[wv][1][ln * 64 + (((ss * 4 + quad) ^ (ln & 7)) << 3)];
    }
    lh = __builtin_amdgcn_mfma_f32_16x16x32_bf16(pfh[0], onesb, lh, 0, 0, 0);
    lh = __builtin_amdgcn_mfma_f32_16x16x32_bf16(pfh[1], onesb, lh, 0, 0, 0);
    if (lo_act) {
      ll = __builtin_amdgcn_mfma_f32_16x16x32_bf16(pfl[0], onesb, ll, 0, 0, 0);
      ll = __builtin_amdgcn_mfma_f32_16x16x32_bf16(pfl[1], onesb, ll, 0, 0, 0);
    }
#pragma unroll
    for (int dt = 0; dt < 8; ++dt) {
      bf16x8 vb[2];
      const u16* vp = &Vs[(dt * 16 + ln) * 64];
#pragma unroll
      for (int ss = 0; ss < 2; ++ss)
        vb[ss] = *(const bf16x8*)(vp + (((quad + 4 * ss) ^ (ln & 7)) << 3));
#pragma unroll
      for (int ss = 0; ss < 2; ++ss)
        oh[dt] = __builtin_amdgcn_mfma_f32_16x16x32_bf16(pfh[ss], vb[ss], oh[dt], 0, 0, 0);
      if (lo_act) {
#pragma unroll
        for (int ss = 0; ss < 2; ++ss)
          ol[dt] = __builtin_amdgcn_mfma_f32_16x16x32_bf16(pfl[ss], vb[ss], ol[dt], 0, 0, 0);
      }
    }
    __syncthreads();
  }
  float rh[4], rl[4];
#pragma unroll
  for (int r = 0; r < 4; ++r) { rh[r] = 1.f / lh[r]; rl[r] = 1.f / ll[r]; }
#pragma unroll
  for (int dt = 0; dt < 8; ++dt)
#pragma unroll
    for (int r = 0; r < 4; ++r) {
      long rowh = (long)b * T_SEQ + qhi + quad * 4 + r;
      long rowl = (long)b * T_SEQ + qlo + quad * 4 + r;
      Og[rowh * (NH * HD) + h * HD + dt * 16 + ln] = f2b(oh[dt][r] * rh[r]);
      Og[rowl * (NH * HD) + h * HD + dt * 16 + ln] = f2b(ol[dt][r] * rl[r]);
    }
}

extern "C" void kernel_launch(void* const* d_in, const int* in_sizes, int n_in,
                              void* d_out, int out_size, void* d_ws, size_t ws_size,
                              hipStream_t stream) {
  const float* x  = (const float*)d_in[0];
  const float* Wq = (const float*)d_in[1];
  const float* Wk = (const float*)d_in[2];
  const float* Wv = (const float*)d_in[3];
  const float* Wo = (const float*)d_in[4];
  float* out = (float*)d_out;
  char* ws = (char*)d_ws;
  // workspace layout (bytes)
  u16* WT  = (u16*)(ws + 0);          // [3072][2048] bf16  (Wq^T | Wk^T | Wv^T)
  u16* Wot = (u16*)(ws + 12582912);   // [2048][2048] bf16
  u16* Cq  = (u16*)(ws + 20971520);   // [4096][3072] bf16 ; later attn [4096][2048]
  u16* Xb  = (u16*)(ws + 46137344);   // [4096][2048] bf16 ; later Q [B,NH,T,HD]
  u16* Kb  = (u16*)(ws + 62914560);   // [B,NKV,T,HD] bf16
  u16* Vtb = (u16*)(ws + 67108864);   // [B,NKV,HD,T] bf16
  u16* Qb = Xb;    // alias: Xb dead after QKV GEMM
  u16* attn = Cq;  // alias: Cqkv dead after rope/vtrans

  k_cvt_x<<<8192, 256, 0, stream>>>(x, Xb, MROWS * DM);
  k_tw4<<<dim3(1, 64, 160), dim3(32, 8), 0, stream>>>(Wq, Wk, Wv, Wo, WT, Wot);

  // QKV projection: 256x256 tiles -> 16x12 = 192 blocks
  k_gemm8<256, u16><<<dim3(16, 12), 512, 0, stream>>>(Xb, WT, Cq, MROWS, NQKV, DM);

  k_rope2<<<20480, 256, 0, stream>>>(Cq, Qb, Kb);
  k_vt<<<dim3(64, 4, 8), dim3(32, 8), 0, stream>>>(Cq, Vtb);

  k_attn<<<dim3(16, 32), 256, 0, stream>>>(Qb, Kb, Vtb, attn);

  // output projection: 256x128 tiles -> 16x16 = 256 blocks (exactly 1/CU)
  k_gemm8<128, float><<<dim3(16, 16), 512, 0, stream>>>(attn, Wot, out, MROWS, DM, 2048);
}